// Round 9
// baseline (328.507 us; speedup 1.0000x reference)
//
#include <hip/hip_runtime.h>

typedef unsigned short u16;
typedef short bf16x8 __attribute__((ext_vector_type(8)));
typedef float f32x4 __attribute__((ext_vector_type(4)));
typedef u16 u16x8 __attribute__((ext_vector_type(8)));
typedef u16 u16x4 __attribute__((ext_vector_type(4)));

#define B_ 4
#define S_ 4096
#define E_ 1024
#define H_ 16
#define D_ 64
#define M_ 16384
#define N_ 3072
#define K_ 1024

__device__ __forceinline__ u16 f2b(float f) {
    unsigned x = __builtin_bit_cast(unsigned, f);
    return (u16)((x + 0x7fffu + ((x >> 16) & 1u)) >> 16);   // RNE
}
__device__ __forceinline__ float b2f(u16 u) {
    unsigned x = ((unsigned)u) << 16;
    return __builtin_bit_cast(float, x);
}
__device__ __forceinline__ float phi_f(float x) { return x > 0.f ? x + 1.f : __expf(x); }

__device__ __forceinline__ void gload16(const void* g, void* l) {
    __builtin_amdgcn_global_load_lds((const __attribute__((address_space(1))) void*)g,
                                     (__attribute__((address_space(3))) void*)l, 16, 0, 0);
}

#define MEMFENCE asm volatile("" ::: "memory")
#define BAR { MEMFENCE; __builtin_amdgcn_s_barrier(); MEMFENCE; }
#define LGKM0 { asm volatile("s_waitcnt lgkmcnt(0)" ::: "memory"); \
                __builtin_amdgcn_sched_barrier(0); }
#define VMCNT(n) asm volatile("s_waitcnt vmcnt(" #n ")" ::: "memory")

// device-scope grid sync primitives (all 256 blocks co-resident: grid == CUs,
// 128KB LDS -> 1 block/CU).  G16: cross-XCD visibility = threadfence + agent
// scope atomics.
__device__ __forceinline__ void grid_arrive(unsigned* c) {
    __threadfence();
    __syncthreads();
    if (threadIdx.x == 0)
        __hip_atomic_fetch_add(c, 1u, __ATOMIC_RELEASE, __HIP_MEMORY_SCOPE_AGENT);
}
__device__ __forceinline__ void grid_wait(unsigned* c, unsigned target) {
    if (threadIdx.x == 0)
        while (__hip_atomic_load(c, __ATOMIC_ACQUIRE, __HIP_MEMORY_SCOPE_AGENT) < target)
            __builtin_amdgcn_s_sleep(8);
    __syncthreads();
    __threadfence();
}

// ---------------- kernel 1: fp32 -> bf16 convert ----------------
__global__ void cvt_bf16(const float* __restrict__ in, u16* __restrict__ out, int n8) {
    int stride = gridDim.x * blockDim.x;
    for (int i = blockIdx.x * blockDim.x + threadIdx.x; i < n8; i += stride) {
        const float4* p = (const float4*)(in + (size_t)i * 8);
        float4 a = p[0], b = p[1];
        u16x8 o;
        o[0] = f2b(a.x); o[1] = f2b(a.y); o[2] = f2b(a.z); o[3] = f2b(a.w);
        o[4] = f2b(b.x); o[5] = f2b(b.y); o[6] = f2b(b.z); o[7] = f2b(b.w);
        *(u16x8*)(out + (size_t)i * 8) = o;
    }
}

// ---------------- shared 256^2-tile 8-phase GEMM machinery (R5/R6) ----------------

#define RD_A(BO, MI0) { _Pragma("unroll") for (int m_ = 0; m_ < 4; ++m_) { \
    av[m_][0] = *(const bf16x8*)(aB + (BO) + (MI0 + m_) * 2048 + pc0); \
    av[m_][1] = *(const bf16x8*)(aB + (BO) + (MI0 + m_) * 2048 + pc1); } }

#define RD_B01(BO) { _Pragma("unroll") for (int n_ = 0; n_ < 2; ++n_) { \
    b01[n_][0] = *(const bf16x8*)(bB + (BO) + n_ * 2048 + pc0); \
    b01[n_][1] = *(const bf16x8*)(bB + (BO) + n_ * 2048 + pc1); } }

#define RD_B23(BO) { _Pragma("unroll") for (int n_ = 0; n_ < 2; ++n_) { \
    b23[n_][0] = *(const bf16x8*)(bB + (BO) + (2 + n_) * 2048 + pc0); \
    b23[n_][1] = *(const bf16x8*)(bB + (BO) + (2 + n_) * 2048 + pc1); } }

#define ST_A(TT, HI, BO) { \
    gload16(gA + (size_t)((HI) * 64) * K_ + (TT) * 64, lds + (BO) + (HI) * 8192 + t16); \
    gload16(gA + (size_t)((HI) * 64 + 128) * K_ + (TT) * 64, lds + (BO) + 16384 + (HI) * 8192 + t16); }

#define ST_B(TT, PR, BO) { \
    gload16(gB + (size_t)((PR) * 128) * K_ + (TT) * 64, lds + (BO) + 32768 + (PR) * 16384 + t16); \
    gload16(gB + (size_t)((PR) * 128 + 64) * K_ + (TT) * 64, lds + (BO) + 32768 + (PR) * 16384 + 8192 + t16); }

#define MM16(MI0, NI0, BV) { __builtin_amdgcn_s_setprio(1); \
    _Pragma("unroll") for (int m_ = 0; m_ < 4; ++m_) \
    _Pragma("unroll") for (int n_ = 0; n_ < 2; ++n_) \
    _Pragma("unroll") for (int h_ = 0; h_ < 2; ++h_) \
        acc[(MI0) + m_][(NI0) + n_] = __builtin_amdgcn_mfma_f32_16x16x32_bf16( \
            av[m_][h_], BV[n_][h_], acc[(MI0) + m_][(NI0) + n_], 0, 0, 0); \
    __builtin_amdgcn_s_setprio(0); }

__device__ __forceinline__ void run_tile(
    const u16* gA, const u16* gB, char* lds, int t16,
    const char* aB, const char* bB, int pc0, int pc1, f32x4 (&acc)[8][4])
{
    bf16x8 av[4][2], b01[2][2], b23[2][2];
    ST_A(0, 0, 0); ST_B(0, 0, 0); ST_B(0, 1, 0); ST_A(0, 1, 0);
    ST_A(1, 0, 65536); ST_B(1, 0, 65536);
    VMCNT(4);
    __builtin_amdgcn_s_barrier();
    MEMFENCE;
#pragma unroll 1
    for (int kt = 0; kt < 16; kt += 2) {
        int tp2 = kt + 2 < 16 ? kt + 2 : 15;
        int tp3 = kt + 3 < 16 ? kt + 3 : 15;
        RD_A(0, 0); RD_B01(0); ST_A(kt + 1, 1, 65536); BAR; LGKM0; MM16(0, 0, b01);
        RD_B23(0);  ST_B(kt + 1, 1, 65536);            BAR; LGKM0; MM16(0, 2, b23);
        RD_A(0, 4); ST_A(tp2, 0, 0);                   BAR; LGKM0; MM16(4, 2, b23);
        ST_B(tp2, 0, 0); VMCNT(4);                     BAR; LGKM0; MM16(4, 0, b01);
        RD_A(65536, 0); RD_B01(65536); ST_A(tp2, 1, 0); BAR; LGKM0; MM16(0, 0, b01);
        RD_B23(65536);  ST_B(tp2, 1, 0);                BAR; LGKM0; MM16(0, 2, b23);
        RD_A(65536, 4); ST_A(tp3, 0, 65536);            BAR; LGKM0; MM16(4, 2, b23);
        ST_B(tp3, 0, 65536); VMCNT(4);                  BAR; LGKM0; MM16(4, 0, b01);
    }
    VMCNT(0);
    __builtin_amdgcn_s_barrier();
    MEMFENCE;
}

// ---------------- kernel 2: everything after cvt, single dispatch ----------------
// Per block (tm,g): V-tile -> VT; K-tile -> kk LDS -> kv/ksum partials;
// arrive cnt1; [64 reducer blocks: wait cnt1==256, reduce -> KVB, arrive cnt2];
// Q-tile; pack kq16; wait cnt2==64; stage KVB; attn; Out.
__global__ __launch_bounds__(512, 2) void gemm_all(
    const u16* __restrict__ Abf, const u16* __restrict__ Wbf,
    const float* __restrict__ bias, const float* __restrict__ mask,
    u16* VT, float* KVP, float* KSP, u16* KVB, unsigned* cnt,
    float* __restrict__ Out)
{
    __shared__ __align__(16) char lds[131072];

    int wg  = blockIdx.x;                 // 256 blocks, 1/CU
    int xcd = wg & 7, ii = wg >> 3;
    int tm  = xcd * 8 + (ii >> 2);
    int g   = ii & 3;
    int m0  = tm << 8;
    int b   = tm >> 4;
    int s0  = (tm & 15) << 8;

    int t = threadIdx.x;
    int l = t & 63, wid = t >> 6;
    int wr = wid >> 2, wc = wid & 3;
    int lg = l >> 4, lr = l & 15;

    int srow  = t >> 3;
    int scolE = ((t & 7) ^ (srow & 7)) << 3;
    int t16   = t * 16;

    const u16* gA = Abf + (size_t)(m0 + srow) * K_ + scolE;
    const char* aB = lds + (wr * 128 + lr) * 128;
    const char* bB = lds + 32768 + (wc * 64 + lr) * 128;
    int pc0 = (lg * 16) ^ ((lr & 7) << 4);
    int pc1 = pc0 ^ 64;

    // ===== tile V =====
    {
        int n0 = 2048 + g * 256;
        const u16* gB = Wbf + (size_t)(n0 + srow) * K_ + scolE;
        f32x4 acc[8][4] = {};
        run_tile(gA, gB, lds, t16, aB, bB, pc0, pc1, acc);
        float bv[4];
#pragma unroll
        for (int ni = 0; ni < 4; ++ni) bv[ni] = bias[n0 + wc * 64 + ni * 16 + lr];
        int h = g * 4 + wc;
#pragma unroll
        for (int mi = 0; mi < 8; ++mi) {
            int sbase = s0 + wr * 128 + mi * 16 + lg * 4;
#pragma unroll
            for (int ni = 0; ni < 4; ++ni) {
                u16x4 o;
#pragma unroll
                for (int j = 0; j < 4; ++j) o[j] = f2b(acc[mi][ni][j] + bv[ni]);
                int d = ni * 16 + lr;
                *(u16x4*)(VT + ((size_t)((b * H_ + h) * D_ + d)) * S_ + sbase) = o;
            }
        }
    }

    // ===== tile K -> kk in LDS =====
    {
        int n0 = 1024 + g * 256;
        const u16* gB = Wbf + (size_t)(n0 + srow) * K_ + scolE;
        f32x4 acc[8][4] = {};
        run_tile(gA, gB, lds, t16, aB, bB, pc0, pc1, acc);
        float bv[4];
#pragma unroll
        for (int ni = 0; ni < 4; ++ni) bv[ni] = bias[n0 + wc * 64 + ni * 16 + lr];
        // kk LDS: [head=wc][d][s], byte = wc*32768 + d*512 + (s*2 ^ ((d&7)<<4))
#pragma unroll
        for (int mi = 0; mi < 8; ++mi) {
            int sl0 = wr * 128 + mi * 16 + lg * 4;
            float mk[4];
#pragma unroll
            for (int j = 0; j < 4; ++j) mk[j] = mask[m0 + sl0 + j];
#pragma unroll
            for (int ni = 0; ni < 4; ++ni) {
                int d = ni * 16 + lr;
                u16x4 o;
#pragma unroll
                for (int j = 0; j < 4; ++j)
                    o[j] = f2b(phi_f((acc[mi][ni][j] + bv[ni]) * mk[j]));
                *(u16x4*)(lds + wc * 32768 + d * 512 + ((sl0 * 2) ^ ((d & 7) << 4))) = o;
            }
        }
    }
    __syncthreads();

    // ===== kv + ksum partials (kk from LDS, v from VT just written) =====
    {
        int head = wid & 3, mh = wid >> 2;
        int bh = b * 16 + g * 4 + head;
        f32x4 akv[2][4] = {};
        const u16* vbase = VT + ((size_t)(bh * 64 + mh * 32 + lr)) * S_ + s0;
#pragma unroll
        for (int ks = 0; ks < 8; ++ks) {
            bf16x8 vf[2];
#pragma unroll
            for (int mi = 0; mi < 2; ++mi)
                vf[mi] = *(const bf16x8*)(vbase + (size_t)mi * 16 * S_ + ks * 32 + lg * 8);
#pragma unroll
            for (int ni = 0; ni < 4; ++ni) {
                int dd = ni * 16 + lr;
                bf16x8 kf = *(const bf16x8*)(lds + head * 32768 + dd * 512 +
                                             ((ks * 64 + lg * 16) ^ ((dd & 7) << 4)));
                akv[0][ni] = __builtin_amdgcn_mfma_f32_16x16x32_bf16(vf[0], kf, akv[0][ni], 0, 0, 0);
                akv[1][ni] = __builtin_amdgcn_mfma_f32_16x16x32_bf16(vf[1], kf, akv[1][ni], 0, 0, 0);
            }
        }
        float* kvp = KVP + ((size_t)(tm & 15) * 64 + bh) * 4096;
#pragma unroll
        for (int mi = 0; mi < 2; ++mi)
#pragma unroll
            for (int ni = 0; ni < 4; ++ni)
#pragma unroll
                for (int j = 0; j < 4; ++j)
                    kvp[(mh * 32 + mi * 16 + lg * 4 + j) * 64 + ni * 16 + lr] = akv[mi][ni][j];
        int hd = t >> 7, dd2 = (t >> 1) & 63, hf = t & 1;
        float ksm = 0.f;
#pragma unroll
        for (int i = 0; i < 16; ++i) {
            bf16x8 kk8 = *(const bf16x8*)(lds + hd * 32768 + dd2 * 512 +
                                          ((hf * 256 + i * 16) ^ ((dd2 & 7) << 4)));
#pragma unroll
            for (int e = 0; e < 8; ++e) ksm += b2f((u16)kk8[e]);
        }
        ksm += __shfl_xor(ksm, 1);
        if (!hf) KSP[(tm & 15) * 4096 + (b * 16 + g * 4 + hd) * 64 + dd2] = ksm;
    }

    // ===== publish partials =====
    grid_arrive(cnt);                       // cnt[0]

    // ===== 64 reducer blocks: KVP/KSP -> KVB (bf16, pre-swizzled) =====
    if ((tm & 3) == 0) {
        grid_wait(cnt, 256);
        int bh = b * 16 + g * 4 + ((tm >> 2) & 3);
        int d = t & 63, mg = t >> 6;        // 8 row-groups x 8 rows
#pragma unroll 1
        for (int i = 0; i < 8; ++i) {
            int m = mg * 8 + i;
            float s = 0.f;
#pragma unroll
            for (int c = 0; c < 16; ++c)
                s += KVP[((size_t)c * 64 + bh) * 4096 + m * 64 + d];
            KVB[((size_t)bh * 80 + m) * 64 + (d ^ ((m & 7) << 3))] = f2b(s);
        }
        if (mg == 0) {
            float s = 0.f;
#pragma unroll
            for (int c = 0; c < 16; ++c) s += KSP[c * 4096 + bh * 64 + d];
            KVB[((size_t)bh * 80 + 64) * 64 + d] = f2b(s);   // m=64 -> m&7==0
        }
        for (int i = t; i < 960; i += 512) {
            int m = 65 + (i >> 6), dd = i & 63;
            KVB[((size_t)bh * 80 + m) * 64 + (dd ^ ((m & 7) << 3))] = 0;
        }
        grid_arrive(cnt + 1);               // cnt[1]
    }

    // ===== tile Q -> kq16 in registers =====
    int n0 = g * 256;
    const u16* gB = Wbf + (size_t)(n0 + srow) * K_ + scolE;
    u16x4 kq16[8][4];
    {
        f32x4 acc[8][4] = {};
        run_tile(gA, gB, lds, t16, aB, bB, pc0, pc1, acc);
        float bv[4];
#pragma unroll
        for (int ni = 0; ni < 4; ++ni) bv[ni] = bias[n0 + wc * 64 + ni * 16 + lr];
        // pack now: acc (128 regs) dies here (R7 spill lesson)
#pragma unroll
        for (int mi = 0; mi < 8; ++mi)
#pragma unroll
            for (int ni = 0; ni < 4; ++ni) {
                u16x4 o;
#pragma unroll
                for (int j = 0; j < 4; ++j)
                    o[j] = f2b(phi_f(acc[mi][ni][j] + bv[ni]));
                kq16[mi][ni] = o;
            }
    }

    // ===== wait for KVB, stage it, attn epilogue =====
    grid_wait(cnt + 1, 64);
    {
        const u16* kvbg = KVB + (size_t)(b * 16 + g * 4) * 80 * 64;
#pragma unroll
        for (int i = 0; i < 5; ++i)
            gload16(kvbg + i * 4096 + t * 8, lds + i * 8192 + t16);
    }
    VMCNT(0);
    __syncthreads();

    // two rounds of 128 s-rows: kq -> LDS [s_loc][head][d] at offset 40960
#pragma unroll
    for (int r = 0; r < 2; ++r) {
        __syncthreads();                  // prior round's reads complete
        if (wr == r) {
#pragma unroll
            for (int mi = 0; mi < 8; ++mi)
#pragma unroll
                for (int j = 0; j < 4; ++j) {
                    int sl = mi * 16 + lg * 4 + j;
                    int swz = (sl & 7) << 4;
#pragma unroll
                    for (int ni = 0; ni < 4; ++ni) {
                        int d2 = (ni * 16 + lr) * 2;
                        *(u16*)(lds + 40960 + sl * 512 + wc * 128 + (d2 ^ swz)) =
                            (u16)kq16[mi][ni][j];
                    }
                }
        }
        __syncthreads();

        f32x4 a2[4][5] = {};
#pragma unroll
        for (int kh = 0; kh < 2; ++kh) {
            bf16x8 af[4];
#pragma unroll
            for (int mi2 = 0; mi2 < 4; ++mi2) {
                int sl = wr * 64 + mi2 * 16 + lr;
                af[mi2] = *(const bf16x8*)(lds + 40960 + sl * 512 + wc * 128 +
                                           ((kh * 64 + lg * 16) ^ ((sl & 7) << 4)));
            }
#pragma unroll
            for (int ni2 = 0; ni2 < 5; ++ni2) {
                int m = ni2 * 16 + lr;
                bf16x8 bf_ = *(const bf16x8*)(lds + wc * 10240 + m * 128 +
                                              ((kh * 64 + lg * 16) ^ ((m & 7) << 4)));
#pragma unroll
                for (int mi2 = 0; mi2 < 4; ++mi2)
                    a2[mi2][ni2] = __builtin_amdgcn_mfma_f32_16x16x32_bf16(
                        af[mi2], bf_, a2[mi2][ni2], 0, 0, 0);
            }
        }
        // den (ksum column), divide, store fp32
#pragma unroll
        for (int mi2 = 0; mi2 < 4; ++mi2)
#pragma unroll
            for (int j = 0; j < 4; ++j) {
                float den = __shfl(a2[mi2][4][j], l & 48);
                float z = 1.f / (den + 1e-6f);
                int sg = (tm & 15) * 256 + r * 128 + wr * 64 + mi2 * 16 + lg * 4 + j;
                float* op = Out + ((size_t)b * S_ + sg) * E_ + g * 256 + wc * 64;
#pragma unroll
                for (int ni2 = 0; ni2 < 4; ++ni2)
                    op[ni2 * 16 + lr] = a2[mi2][ni2][j] * z;
            }
    }
}

extern "C" void kernel_launch(void* const* d_in, const int* in_sizes, int n_in,
                              void* d_out, int out_size, void* d_ws, size_t ws_size,
                              hipStream_t stream)
{
    const float* inputs = (const float*)d_in[0];
    const float* mask   = (const float*)d_in[1];
    const float* w_qkv  = (const float*)d_in[2];
    const float* b_qkv  = (const float*)d_in[3];

    u16* Abf = (u16*)d_ws;                          // 16777216 bf16 (32 MB)
    u16* Wbf = Abf + (size_t)M_ * K_;               // 3145728 bf16 (6 MB)
    float* KVP = (float*)(Wbf + (size_t)N_ * K_);   // 16*64*4096 f32 (16 MB)
    float* KSP = KVP + 16 * 64 * 4096;              // 16*4096 f32
    u16* KVB   = (u16*)(KSP + 16 * 4096);           // 64*80*64 bf16 (640 KB)
    unsigned* cnt = (unsigned*)(KVB + 64 * 80 * 64);// 2 counters

    // V^T lives in d_out (bf16, 33.5 MB of the 67 MB fp32 output buffer);
    // all VT reads happen before cnt1==256, all Out writes after cnt2 -> safe.
    u16* VT = (u16*)d_out;

    hipMemsetAsync(cnt, 0, 8, stream);              // re-zero every launch (graph-safe)
    cvt_bf16<<<2048, 256, 0, stream>>>(inputs, Abf, M_ * K_ / 8);
    cvt_bf16<<<768, 256, 0, stream>>>(w_qkv, Wbf, N_ * K_ / 8);
    gemm_all<<<256, 512, 0, stream>>>(Abf, Wbf, b_qkv, mask, VT, KVP, KSP, KVB,
                                      cnt, (float*)d_out);
}

// Round 10
// 186.285 us; speedup vs baseline: 1.7635x; 1.7635x over previous
//
#include <hip/hip_runtime.h>

typedef unsigned short u16;
typedef short bf16x8 __attribute__((ext_vector_type(8)));
typedef float f32x4 __attribute__((ext_vector_type(4)));
typedef u16 u16x8 __attribute__((ext_vector_type(8)));
typedef u16 u16x4 __attribute__((ext_vector_type(4)));

#define B_ 4
#define S_ 4096
#define E_ 1024
#define H_ 16
#define D_ 64
#define M_ 16384
#define N_ 3072
#define K_ 1024

__device__ __forceinline__ u16 f2b(float f) {
    unsigned x = __builtin_bit_cast(unsigned, f);
    return (u16)((x + 0x7fffu + ((x >> 16) & 1u)) >> 16);   // RNE
}
__device__ __forceinline__ float b2f(u16 u) {
    unsigned x = ((unsigned)u) << 16;
    return __builtin_bit_cast(float, x);
}
__device__ __forceinline__ float phi_f(float x) { return x > 0.f ? x + 1.f : __expf(x); }

__device__ __forceinline__ void gload16(const void* g, void* l) {
    __builtin_amdgcn_global_load_lds((const __attribute__((address_space(1))) void*)g,
                                     (__attribute__((address_space(3))) void*)l, 16, 0, 0);
}

#define MEMFENCE asm volatile("" ::: "memory")
#define BAR { MEMFENCE; __builtin_amdgcn_s_barrier(); MEMFENCE; }
#define VMCNT(n) asm volatile("s_waitcnt vmcnt(" #n ")" ::: "memory")
#define LGKM(n) asm volatile("s_waitcnt lgkmcnt(" #n ")" ::: "memory")
#define SB0 __builtin_amdgcn_sched_barrier(0)

// ---------------- kernel 1: fp32 -> bf16 convert ----------------
__global__ void cvt_bf16(const float* __restrict__ in, u16* __restrict__ out, int n8) {
    int stride = gridDim.x * blockDim.x;
    for (int i = blockIdx.x * blockDim.x + threadIdx.x; i < n8; i += stride) {
        const float4* p = (const float4*)(in + (size_t)i * 8);
        float4 a = p[0], b = p[1];
        u16x8 o;
        o[0] = f2b(a.x); o[1] = f2b(a.y); o[2] = f2b(a.z); o[3] = f2b(a.w);
        o[4] = f2b(b.x); o[5] = f2b(b.y); o[6] = f2b(b.z); o[7] = f2b(b.w);
        *(u16x8*)(out + (size_t)i * 8) = o;
    }
}

// ---------------- 256^2-tile 8-phase GEMM, R10: read-ahead + counted lgkm ----------
// R5 arithmetic: per K-tile/CU MFMA=2483cy, LDS-reads=1536-2300cy; the old
// {RD; BAR; lgkmcnt(0); MM} body SERIALIZED them.  New phase body:
//   { ST(sched); [vmcnt(4)@P4/P8]; BAR; RD(frags for phase p+1);
//     lgkmcnt(N = reads just issued); sched_barrier; MM(p) }
// -> MFMA(p) overlaps the LDS-pipe time of reads(p+1).
// Quadrant order: tile t (0,0),(0,2),(4,2),(4,0); tile t+1 (0,2),(0,0),(4,0),(4,2)
// -> single b01/b23 register set, two alternating A sets (avX/avY).
// RAW: reads of a freshly staged region sit after a vmcnt(4)+BAR that proves it
// landed.  WAR: every region's reads are lgkm-completed >=2 barriers before its
// re-staging (verified per phase; see derivation in journal).

#define RD_A_TO(DST, BO, MI0) { _Pragma("unroll") for (int m_ = 0; m_ < 4; ++m_) { \
    DST[m_][0] = *(const bf16x8*)(aB + (BO) + (MI0 + m_) * 2048 + pc0); \
    DST[m_][1] = *(const bf16x8*)(aB + (BO) + (MI0 + m_) * 2048 + pc1); } }

#define RD_B_TO(DST, BO, NI0) { _Pragma("unroll") for (int n_ = 0; n_ < 2; ++n_) { \
    DST[n_][0] = *(const bf16x8*)(bB + (BO) + (NI0 + n_) * 2048 + pc0); \
    DST[n_][1] = *(const bf16x8*)(bB + (BO) + (NI0 + n_) * 2048 + pc1); } }

#define ST_A(TT, HI, BO) { \
    gload16(gA + (size_t)((HI) * 64) * K_ + (TT) * 64, lds + (BO) + (HI) * 8192 + t16); \
    gload16(gA + (size_t)((HI) * 64 + 128) * K_ + (TT) * 64, lds + (BO) + 16384 + (HI) * 8192 + t16); }

#define ST_B(TT, PR, BO) { \
    gload16(gB + (size_t)((PR) * 128) * K_ + (TT) * 64, lds + (BO) + 32768 + (PR) * 16384 + t16); \
    gload16(gB + (size_t)((PR) * 128 + 64) * K_ + (TT) * 64, lds + (BO) + 32768 + (PR) * 16384 + 8192 + t16); }

#define MM16(MI0, NI0, AV, BV) { __builtin_amdgcn_s_setprio(1); \
    _Pragma("unroll") for (int m_ = 0; m_ < 4; ++m_) \
    _Pragma("unroll") for (int n_ = 0; n_ < 2; ++n_) \
    _Pragma("unroll") for (int h_ = 0; h_ < 2; ++h_) \
        acc[(MI0) + m_][(NI0) + n_] = __builtin_amdgcn_mfma_f32_16x16x32_bf16( \
            AV[m_][h_], BV[n_][h_], acc[(MI0) + m_][(NI0) + n_], 0, 0, 0); \
    __builtin_amdgcn_s_setprio(0); }

__device__ __forceinline__ void run_tile(
    const u16* gA, const u16* gB, char* lds, int t16,
    const char* aB, const char* bB, int pc0, int pc1, f32x4 (&acc)[8][4])
{
    bf16x8 avX[4][2], avY[4][2], b01[2][2], b23[2][2];
    // prologue: buf0(t0) full (8 loads), buf1(t1) A-lo + B-h1 (4 loads)
    ST_A(0, 0, 0); ST_B(0, 0, 0); ST_B(0, 1, 0); ST_A(0, 1, 0);
    ST_A(1, 0, 65536); ST_B(1, 0, 65536);
    VMCNT(4);                        // buf0's 8 oldest landed
    __builtin_amdgcn_s_barrier();
    MEMFENCE;
    RD_A_TO(avX, 0, 0); RD_B_TO(b01, 0, 0);   // P1 frags, issued ahead
#pragma unroll 1
    for (int kt = 0; kt < 16; kt += 2) {
        int tp2 = kt + 2 < 16 ? kt + 2 : 15;   // junk-clamp, positionally safe
        int tp3 = kt + 3 < 16 ? kt + 3 : 15;
        // P1: MM(0,0)=avX*b01 ; read b23(t,B0) for P2
        ST_A(kt + 1, 1, 65536); BAR; RD_B_TO(b23, 0, 2);
        LGKM(4); SB0; MM16(0, 0, avX, b01);
        // P2: MM(0,2)=avX*b23 ; read A47(t,B0) for P3
        ST_B(kt + 1, 1, 65536); BAR; RD_A_TO(avY, 0, 4);
        LGKM(8); SB0; MM16(0, 2, avX, b23);
        // P3: MM(4,2)=avY*b23
        ST_A(tp2, 0, 0); BAR;
        LGKM(0); SB0; MM16(4, 2, avY, b23);
        // P4: MM(4,0)=avY*b01 ; read A03(t+1,B1)+b23(t+1,B1) for P5
        ST_B(tp2, 0, 0); VMCNT(4); BAR; RD_A_TO(avX, 65536, 0); RD_B_TO(b23, 65536, 2);
        LGKM(12); SB0; MM16(4, 0, avY, b01);
        // P5: MM(0,2)=avX*b23 ; read b01(t+1,B1) for P6
        ST_A(tp2, 1, 0); BAR; RD_B_TO(b01, 65536, 0);
        LGKM(4); SB0; MM16(0, 2, avX, b23);
        // P6: MM(0,0)=avX*b01 ; read A47(t+1,B1) for P7
        ST_B(tp2, 1, 0); BAR; RD_A_TO(avY, 65536, 4);
        LGKM(8); SB0; MM16(0, 0, avX, b01);
        // P7: MM(4,0)=avY*b01
        ST_A(tp3, 0, 65536); BAR;
        LGKM(0); SB0; MM16(4, 0, avY, b01);
        // P8: MM(4,2)=avY*b23 ; read A03(t+2,B0)+b01(t+2,B0) for next P1
        ST_B(tp3, 0, 65536); VMCNT(4); BAR; RD_A_TO(avX, 0, 0); RD_B_TO(b01, 0, 0);
        LGKM(12); SB0; MM16(4, 2, avY, b23);
    }
    VMCNT(0);                        // junk prefetches must land before LDS reuse
    LGKM(0);                         // drain dangling tile-16 reads
    __builtin_amdgcn_s_barrier();
    MEMFENCE;
}

// ---------------- kernel 2: fused QKV GEMM + in-block kv/ksum partials (R6) ----------
__global__ __launch_bounds__(512, 2) void gemm_fused(
    const u16* __restrict__ Abf, const u16* __restrict__ Wbf,
    const float* __restrict__ bias, const float* __restrict__ mask,
    u16* __restrict__ KQ, u16* VT,
    float* __restrict__ KVP, float* __restrict__ KSP)
{
    __shared__ __align__(16) char lds[131072];

    int wg  = blockIdx.x;                 // 256 blocks, 1/CU
    int xcd = wg & 7, ii = wg >> 3;
    int tm  = xcd * 8 + (ii >> 2);
    int g   = ii & 3;
    int m0  = tm << 8;
    int b   = tm >> 4;
    int s0  = (tm & 15) << 8;

    int t = threadIdx.x;
    int l = t & 63, wid = t >> 6;
    int wr = wid >> 2, wc = wid & 3;
    int lg = l >> 4, lr = l & 15;

    int srow  = t >> 3;
    int scolE = ((t & 7) ^ (srow & 7)) << 3;   // pre-swizzled source (T2/m173)
    int t16   = t * 16;

    const u16* gA = Abf + (size_t)(m0 + srow) * K_ + scolE;
    const char* aB = lds + (wr * 128 + lr) * 128;
    const char* bB = lds + 32768 + (wc * 64 + lr) * 128;
    int pc0 = (lg * 16) ^ ((lr & 7) << 4);
    int pc1 = pc0 ^ 64;

    // ===== tile V =====
    {
        int n0 = 2048 + g * 256;
        const u16* gB = Wbf + (size_t)(n0 + srow) * K_ + scolE;
        f32x4 acc[8][4] = {};
        run_tile(gA, gB, lds, t16, aB, bB, pc0, pc1, acc);
        float bv[4];
#pragma unroll
        for (int ni = 0; ni < 4; ++ni) bv[ni] = bias[n0 + wc * 64 + ni * 16 + lr];
        int h = g * 4 + wc;
#pragma unroll
        for (int mi = 0; mi < 8; ++mi) {
            int sbase = s0 + wr * 128 + mi * 16 + lg * 4;
#pragma unroll
            for (int ni = 0; ni < 4; ++ni) {
                u16x4 o;
#pragma unroll
                for (int j = 0; j < 4; ++j) o[j] = f2b(acc[mi][ni][j] + bv[ni]);
                int d = ni * 16 + lr;
                *(u16x4*)(VT + ((size_t)((b * H_ + h) * D_ + d)) * S_ + sbase) = o;
            }
        }
    }

    // ===== tile K -> kk in LDS =====
    {
        int n0 = 1024 + g * 256;
        const u16* gB = Wbf + (size_t)(n0 + srow) * K_ + scolE;
        f32x4 acc[8][4] = {};
        run_tile(gA, gB, lds, t16, aB, bB, pc0, pc1, acc);
        float bv[4];
#pragma unroll
        for (int ni = 0; ni < 4; ++ni) bv[ni] = bias[n0 + wc * 64 + ni * 16 + lr];
        // kk LDS: [head=wc][d][s], byte = wc*32768 + d*512 + (s*2 ^ ((d&7)<<4))
#pragma unroll
        for (int mi = 0; mi < 8; ++mi) {
            int sl0 = wr * 128 + mi * 16 + lg * 4;
            float mk[4];
#pragma unroll
            for (int j = 0; j < 4; ++j) mk[j] = mask[m0 + sl0 + j];
#pragma unroll
            for (int ni = 0; ni < 4; ++ni) {
                int d = ni * 16 + lr;
                u16x4 o;
#pragma unroll
                for (int j = 0; j < 4; ++j)
                    o[j] = f2b(phi_f((acc[mi][ni][j] + bv[ni]) * mk[j]));
                *(u16x4*)(lds + wc * 32768 + d * 512 + ((sl0 * 2) ^ ((d & 7) << 4))) = o;
            }
        }
    }
    __syncthreads();

    // ===== kv + ksum partials (kk from LDS, v from VT just written) =====
    {
        int head = wid & 3, mh = wid >> 2;
        int bh = b * 16 + g * 4 + head;
        f32x4 akv[2][4] = {};
        const u16* vbase = VT + ((size_t)(bh * 64 + mh * 32 + lr)) * S_ + s0;
#pragma unroll
        for (int ks = 0; ks < 8; ++ks) {
            bf16x8 vf[2];
#pragma unroll
            for (int mi = 0; mi < 2; ++mi)
                vf[mi] = *(const bf16x8*)(vbase + (size_t)mi * 16 * S_ + ks * 32 + lg * 8);
#pragma unroll
            for (int ni = 0; ni < 4; ++ni) {
                int dd = ni * 16 + lr;
                bf16x8 kf = *(const bf16x8*)(lds + head * 32768 + dd * 512 +
                                             ((ks * 64 + lg * 16) ^ ((dd & 7) << 4)));
                akv[0][ni] = __builtin_amdgcn_mfma_f32_16x16x32_bf16(vf[0], kf, akv[0][ni], 0, 0, 0);
                akv[1][ni] = __builtin_amdgcn_mfma_f32_16x16x32_bf16(vf[1], kf, akv[1][ni], 0, 0, 0);
            }
        }
        float* kvp = KVP + ((size_t)(tm & 15) * 64 + bh) * 4096;
#pragma unroll
        for (int mi = 0; mi < 2; ++mi)
#pragma unroll
            for (int ni = 0; ni < 4; ++ni)
#pragma unroll
                for (int j = 0; j < 4; ++j)
                    kvp[(mh * 32 + mi * 16 + lg * 4 + j) * 64 + ni * 16 + lr] = akv[mi][ni][j];
        int hd = t >> 7, dd2 = (t >> 1) & 63, hf = t & 1;
        float ksm = 0.f;
#pragma unroll
        for (int i = 0; i < 16; ++i) {
            bf16x8 kk8 = *(const bf16x8*)(lds + hd * 32768 + dd2 * 512 +
                                          ((hf * 256 + i * 16) ^ ((dd2 & 7) << 4)));
#pragma unroll
            for (int e = 0; e < 8; ++e) ksm += b2f((u16)kk8[e]);
        }
        ksm += __shfl_xor(ksm, 1);
        if (!hf) KSP[(tm & 15) * 4096 + (b * 16 + g * 4 + hd) * 64 + dd2] = ksm;
    }
    __syncthreads();

    // ===== tile Q -> KQ (row-major bf16) =====
    {
        int n0 = g * 256;
        const u16* gB = Wbf + (size_t)(n0 + srow) * K_ + scolE;
        f32x4 acc[8][4] = {};
        run_tile(gA, gB, lds, t16, aB, bB, pc0, pc1, acc);
        float bv[4];
#pragma unroll
        for (int ni = 0; ni < 4; ++ni) bv[ni] = bias[n0 + wc * 64 + ni * 16 + lr];
#pragma unroll
        for (int mi = 0; mi < 8; ++mi)
#pragma unroll
            for (int j = 0; j < 4; ++j) {
                int row = m0 + wr * 128 + mi * 16 + lg * 4 + j;
#pragma unroll
                for (int ni = 0; ni < 4; ++ni) {
                    int col = n0 + wc * 64 + ni * 16 + lr;
                    KQ[(size_t)row * E_ + col] = f2b(phi_f(acc[mi][ni][j] + bv[ni]));
                }
            }
    }
}

// ---------------- kernel 3: deterministic partial reduce ----------------
__global__ void reduce_kv(const float* __restrict__ KVP, const float* __restrict__ KSP,
                          float* __restrict__ KV, float* __restrict__ KSUM)
{
    int g = blockIdx.x * 256 + threadIdx.x;   // 65536 threads
#pragma unroll 1
    for (int i = g * 4; i < g * 4 + 4; ++i) {
        float s = 0.f;
#pragma unroll
        for (int c = 0; c < 16; ++c) s += KVP[(size_t)c * (64 * 4096) + i];
        KV[i] = s;
    }
    if (g < 4096) {
        float s = 0.f;
#pragma unroll
        for (int c = 0; c < 16; ++c) s += KSP[c * 4096 + g];
        KSUM[g] = s;
    }
}

// ---------------- kernel 4: attn = kq·[kv;ksum] , divide by den ----------------
__global__ __launch_bounds__(256) void attn_out(
    const u16* __restrict__ KQ, const float* __restrict__ KV,
    const float* __restrict__ KSUM, float* __restrict__ Out)
{
    __shared__ __align__(16) u16 kqs[16384];   // 256 x 64 bf16 (32 KB)
    __shared__ __align__(16) u16 bsm[5120];    // 80 x 64 bf16
    __shared__ float den[256];
    int bh = blockIdx.x, ch = blockIdx.y;
    int b = bh >> 4, h = bh & 15;
    int t = threadIdx.x;
    int l = t & 63, w = t >> 6;
    int lg = l >> 4, lr = l & 15;
    size_t row0 = (size_t)b * S_ + ch * 256;
    int srow = t >> 3, scol = (t & 7) << 3;
#pragma unroll
    for (int i = 0; i < 8; ++i)
        gload16(KQ + (row0 + srow + i * 32) * E_ + h * 64 + scol, kqs + i * 2048 + t * 8);

    const float* kvg = KV + bh * 4096;
#pragma unroll
    for (int ii = 0; ii < 16; ii += 4) {
        float4 v = *(const float4*)(kvg + t * 16 + ii);
        u16x4 o; o[0] = f2b(v.x); o[1] = f2b(v.y); o[2] = f2b(v.z); o[3] = f2b(v.w);
        *(u16x4*)&bsm[t * 16 + ii] = o;
    }
    if (t < 64) bsm[4096 + t] = f2b(KSUM[bh * 64 + t]);
    for (int i = t; i < 960; i += 256) bsm[4160 + i] = 0;
    __syncthreads();

    f32x4 acc[4][5] = {};
#pragma unroll
    for (int kh = 0; kh < 2; ++kh) {
        int ko = kh * 32 + lg * 8;
        bf16x8 af[4];
#pragma unroll
        for (int mi = 0; mi < 4; ++mi)
            af[mi] = *(const bf16x8*)&kqs[(w * 64 + mi * 16 + lr) * 64 + ko];
#pragma unroll
        for (int ni = 0; ni < 5; ++ni) {
            bf16x8 bb = *(const bf16x8*)&bsm[(ni * 16 + lr) * 64 + ko];
#pragma unroll
            for (int mi = 0; mi < 4; ++mi)
                acc[mi][ni] = __builtin_amdgcn_mfma_f32_16x16x32_bf16(af[mi], bb, acc[mi][ni], 0, 0, 0);
        }
    }
    if (lr == 0) {
#pragma unroll
        for (int mi = 0; mi < 4; ++mi)
#pragma unroll
            for (int j = 0; j < 4; ++j)
                den[w * 64 + mi * 16 + lg * 4 + j] = acc[mi][4][j];
    }
    __syncthreads();
#pragma unroll
    for (int mi = 0; mi < 4; ++mi)
#pragma unroll
        for (int j = 0; j < 4; ++j) {
            int sl = w * 64 + mi * 16 + lg * 4 + j;
            float z = 1.f / (den[sl] + 1e-6f);
            float* op = Out + (row0 + sl) * E_ + h * 64;
#pragma unroll
            for (int ni = 0; ni < 4; ++ni)
                op[ni * 16 + lr] = acc[mi][ni][j] * z;
        }
}

extern "C" void kernel_launch(void* const* d_in, const int* in_sizes, int n_in,
                              void* d_out, int out_size, void* d_ws, size_t ws_size,
                              hipStream_t stream)
{
    const float* inputs = (const float*)d_in[0];
    const float* mask   = (const float*)d_in[1];
    const float* w_qkv  = (const float*)d_in[2];
    const float* b_qkv  = (const float*)d_in[3];

    u16* Abf = (u16*)d_ws;                          // 16777216 bf16 (32 MB)
    u16* Wbf = Abf + (size_t)M_ * K_;               // 3145728 bf16 (6 MB)
    u16* KQ  = Wbf + (size_t)N_ * K_;               // 16777216 bf16 (32 MB)
    float* KVP  = (float*)(KQ + (size_t)M_ * E_);   // 16*262144 f32 (16 MB)
    float* KSP  = KVP + 16 * 64 * 4096;             // 16*4096 f32
    float* KV   = KSP + 16 * 4096;                  // 262144 f32
    float* KSUM = KV + 64 * 4096;                   // 4096 f32

    // V^T lives in d_out (bf16), consumed inside gemm_fused only;
    // attn_out overwrites d_out with the final fp32 output.
    u16* VT = (u16*)d_out;

    cvt_bf16<<<2048, 256, 0, stream>>>(inputs, Abf, M_ * K_ / 8);
    cvt_bf16<<<768, 256, 0, stream>>>(w_qkv, Wbf, N_ * K_ / 8);
    gemm_fused<<<256, 512, 0, stream>>>(Abf, Wbf, b_qkv, mask, KQ, VT, KVP, KSP);
    reduce_kv<<<256, 256, 0, stream>>>(KVP, KSP, KV, KSUM);
    attn_out<<<dim3(64, 16), 256, 0, stream>>>(KQ, KV, KSUM, (float*)d_out);
}

// Round 11
// 154.890 us; speedup vs baseline: 2.1209x; 1.2027x over previous
//
#include <hip/hip_runtime.h>

typedef unsigned short u16;
typedef short bf16x8 __attribute__((ext_vector_type(8)));
typedef float f32x4 __attribute__((ext_vector_type(4)));
typedef u16 u16x8 __attribute__((ext_vector_type(8)));
typedef u16 u16x4 __attribute__((ext_vector_type(4)));

#define B_ 4
#define S_ 4096
#define E_ 1024
#define H_ 16
#define D_ 64
#define M_ 16384
#define N_ 3072
#define K_ 1024

// R11 = exact revert to the R6 best-known configuration (156.2 us).
// Schedule-port attempts R4/R5/R10 all failed to beat this run_tile
// (911 TF = documented plain-HIP 2-barrier structure ceiling); R7/R8
// (split GEMM) and R9 (grid-sync fusion) regressed. Do not re-attempt
// without new counter evidence.

__device__ __forceinline__ u16 f2b(float f) {
    unsigned x = __builtin_bit_cast(unsigned, f);
    return (u16)((x + 0x7fffu + ((x >> 16) & 1u)) >> 16);   // RNE
}
__device__ __forceinline__ float b2f(u16 u) {
    unsigned x = ((unsigned)u) << 16;
    return __builtin_bit_cast(float, x);
}
__device__ __forceinline__ float phi_f(float x) { return x > 0.f ? x + 1.f : __expf(x); }

__device__ __forceinline__ void gload16(const void* g, void* l) {
    __builtin_amdgcn_global_load_lds((const __attribute__((address_space(1))) void*)g,
                                     (__attribute__((address_space(3))) void*)l, 16, 0, 0);
}

#define MEMFENCE asm volatile("" ::: "memory")
#define BAR { MEMFENCE; __builtin_amdgcn_s_barrier(); MEMFENCE; }
#define LGKM0 { asm volatile("s_waitcnt lgkmcnt(0)" ::: "memory"); \
                __builtin_amdgcn_sched_barrier(0); }
#define VMCNT(n) asm volatile("s_waitcnt vmcnt(" #n ")" ::: "memory")

// ---------------- kernel 1: fp32 -> bf16 convert ----------------
__global__ void cvt_bf16(const float* __restrict__ in, u16* __restrict__ out, int n8) {
    int stride = gridDim.x * blockDim.x;
    for (int i = blockIdx.x * blockDim.x + threadIdx.x; i < n8; i += stride) {
        const float4* p = (const float4*)(in + (size_t)i * 8);
        float4 a = p[0], b = p[1];
        u16x8 o;
        o[0] = f2b(a.x); o[1] = f2b(a.y); o[2] = f2b(a.z); o[3] = f2b(a.w);
        o[4] = f2b(b.x); o[5] = f2b(b.y); o[6] = f2b(b.z); o[7] = f2b(b.w);
        *(u16x8*)(out + (size_t)i * 8) = o;
    }
}

// ---------------- 256^2-tile 8-phase GEMM machinery (R5 schedule) ----------------

#define RD_A(BO, MI0) { _Pragma("unroll") for (int m_ = 0; m_ < 4; ++m_) { \
    av[m_][0] = *(const bf16x8*)(aB + (BO) + (MI0 + m_) * 2048 + pc0); \
    av[m_][1] = *(const bf16x8*)(aB + (BO) + (MI0 + m_) * 2048 + pc1); } }

#define RD_B01(BO) { _Pragma("unroll") for (int n_ = 0; n_ < 2; ++n_) { \
    b01[n_][0] = *(const bf16x8*)(bB + (BO) + n_ * 2048 + pc0); \
    b01[n_][1] = *(const bf16x8*)(bB + (BO) + n_ * 2048 + pc1); } }

#define RD_B23(BO) { _Pragma("unroll") for (int n_ = 0; n_ < 2; ++n_) { \
    b23[n_][0] = *(const bf16x8*)(bB + (BO) + (2 + n_) * 2048 + pc0); \
    b23[n_][1] = *(const bf16x8*)(bB + (BO) + (2 + n_) * 2048 + pc1); } }

#define ST_A(TT, HI, BO) { \
    gload16(gA + (size_t)((HI) * 64) * K_ + (TT) * 64, lds + (BO) + (HI) * 8192 + t16); \
    gload16(gA + (size_t)((HI) * 64 + 128) * K_ + (TT) * 64, lds + (BO) + 16384 + (HI) * 8192 + t16); }

#define ST_B(TT, PR, BO) { \
    gload16(gB + (size_t)((PR) * 128) * K_ + (TT) * 64, lds + (BO) + 32768 + (PR) * 16384 + t16); \
    gload16(gB + (size_t)((PR) * 128 + 64) * K_ + (TT) * 64, lds + (BO) + 32768 + (PR) * 16384 + 8192 + t16); }

#define MM16(MI0, NI0, BV) { __builtin_amdgcn_s_setprio(1); \
    _Pragma("unroll") for (int m_ = 0; m_ < 4; ++m_) \
    _Pragma("unroll") for (int n_ = 0; n_ < 2; ++n_) \
    _Pragma("unroll") for (int h_ = 0; h_ < 2; ++h_) \
        acc[(MI0) + m_][(NI0) + n_] = __builtin_amdgcn_mfma_f32_16x16x32_bf16( \
            av[m_][h_], BV[n_][h_], acc[(MI0) + m_][(NI0) + n_], 0, 0, 0); \
    __builtin_amdgcn_s_setprio(0); }

__device__ __forceinline__ void run_tile(
    const u16* gA, const u16* gB, char* lds, int t16,
    const char* aB, const char* bB, int pc0, int pc1, f32x4 (&acc)[8][4])
{
    bf16x8 av[4][2], b01[2][2], b23[2][2];
    ST_A(0, 0, 0); ST_B(0, 0, 0); ST_B(0, 1, 0); ST_A(0, 1, 0);
    ST_A(1, 0, 65536); ST_B(1, 0, 65536);
    VMCNT(4);
    __builtin_amdgcn_s_barrier();
    MEMFENCE;
#pragma unroll 1
    for (int kt = 0; kt < 16; kt += 2) {
        int tp2 = kt + 2 < 16 ? kt + 2 : 15;
        int tp3 = kt + 3 < 16 ? kt + 3 : 15;
        RD_A(0, 0); RD_B01(0); ST_A(kt + 1, 1, 65536); BAR; LGKM0; MM16(0, 0, b01);
        RD_B23(0);  ST_B(kt + 1, 1, 65536);            BAR; LGKM0; MM16(0, 2, b23);
        RD_A(0, 4); ST_A(tp2, 0, 0);                   BAR; LGKM0; MM16(4, 2, b23);
        ST_B(tp2, 0, 0); VMCNT(4);                     BAR; LGKM0; MM16(4, 0, b01);
        RD_A(65536, 0); RD_B01(65536); ST_A(tp2, 1, 0); BAR; LGKM0; MM16(0, 0, b01);
        RD_B23(65536);  ST_B(tp2, 1, 0);                BAR; LGKM0; MM16(0, 2, b23);
        RD_A(65536, 4); ST_A(tp3, 0, 65536);            BAR; LGKM0; MM16(4, 2, b23);
        ST_B(tp3, 0, 65536); VMCNT(4);                  BAR; LGKM0; MM16(4, 0, b01);
    }
    VMCNT(0);
    __builtin_amdgcn_s_barrier();
    MEMFENCE;
}

// ---------------- kernel 2: fused QKV GEMM + in-block kv/ksum partials ----------------
__global__ __launch_bounds__(512, 2) void gemm_fused(
    const u16* __restrict__ Abf, const u16* __restrict__ Wbf,
    const float* __restrict__ bias, const float* __restrict__ mask,
    u16* __restrict__ KQ, u16* VT,
    float* __restrict__ KVP, float* __restrict__ KSP)
{
    __shared__ __align__(16) char lds[131072];

    int wg  = blockIdx.x;                 // 256 blocks, 1/CU
    int xcd = wg & 7, ii = wg >> 3;
    int tm  = xcd * 8 + (ii >> 2);
    int g   = ii & 3;
    int m0  = tm << 8;
    int b   = tm >> 4;
    int s0  = (tm & 15) << 8;

    int t = threadIdx.x;
    int l = t & 63, wid = t >> 6;
    int wr = wid >> 2, wc = wid & 3;
    int lg = l >> 4, lr = l & 15;

    int srow  = t >> 3;
    int scolE = ((t & 7) ^ (srow & 7)) << 3;   // pre-swizzled source (T2/m173)
    int t16   = t * 16;

    const u16* gA = Abf + (size_t)(m0 + srow) * K_ + scolE;
    const char* aB = lds + (wr * 128 + lr) * 128;
    const char* bB = lds + 32768 + (wc * 64 + lr) * 128;
    int pc0 = (lg * 16) ^ ((lr & 7) << 4);
    int pc1 = pc0 ^ 64;

    // ===== tile V =====
    {
        int n0 = 2048 + g * 256;
        const u16* gB = Wbf + (size_t)(n0 + srow) * K_ + scolE;
        f32x4 acc[8][4] = {};
        run_tile(gA, gB, lds, t16, aB, bB, pc0, pc1, acc);
        float bv[4];
#pragma unroll
        for (int ni = 0; ni < 4; ++ni) bv[ni] = bias[n0 + wc * 64 + ni * 16 + lr];
        int h = g * 4 + wc;
#pragma unroll
        for (int mi = 0; mi < 8; ++mi) {
            int sbase = s0 + wr * 128 + mi * 16 + lg * 4;
#pragma unroll
            for (int ni = 0; ni < 4; ++ni) {
                u16x4 o;
#pragma unroll
                for (int j = 0; j < 4; ++j) o[j] = f2b(acc[mi][ni][j] + bv[ni]);
                int d = ni * 16 + lr;
                *(u16x4*)(VT + ((size_t)((b * H_ + h) * D_ + d)) * S_ + sbase) = o;
            }
        }
    }

    // ===== tile K -> kk in LDS =====
    {
        int n0 = 1024 + g * 256;
        const u16* gB = Wbf + (size_t)(n0 + srow) * K_ + scolE;
        f32x4 acc[8][4] = {};
        run_tile(gA, gB, lds, t16, aB, bB, pc0, pc1, acc);
        float bv[4];
#pragma unroll
        for (int ni = 0; ni < 4; ++ni) bv[ni] = bias[n0 + wc * 64 + ni * 16 + lr];
        // kk LDS: [head=wc][d][s], byte = wc*32768 + d*512 + (s*2 ^ ((d&7)<<4))
#pragma unroll
        for (int mi = 0; mi < 8; ++mi) {
            int sl0 = wr * 128 + mi * 16 + lg * 4;
            float mk[4];
#pragma unroll
            for (int j = 0; j < 4; ++j) mk[j] = mask[m0 + sl0 + j];
#pragma unroll
            for (int ni = 0; ni < 4; ++ni) {
                int d = ni * 16 + lr;
                u16x4 o;
#pragma unroll
                for (int j = 0; j < 4; ++j)
                    o[j] = f2b(phi_f((acc[mi][ni][j] + bv[ni]) * mk[j]));
                *(u16x4*)(lds + wc * 32768 + d * 512 + ((sl0 * 2) ^ ((d & 7) << 4))) = o;
            }
        }
    }
    __syncthreads();

    // ===== kv + ksum partials (kk from LDS, v from VT just written) =====
    {
        int head = wid & 3, mh = wid >> 2;
        int bh = b * 16 + g * 4 + head;
        f32x4 akv[2][4] = {};
        const u16* vbase = VT + ((size_t)(bh * 64 + mh * 32 + lr)) * S_ + s0;
#pragma unroll
        for (int ks = 0; ks < 8; ++ks) {
            bf16x8 vf[2];
#pragma unroll
            for (int mi = 0; mi < 2; ++mi)
                vf[mi] = *(const bf16x8*)(vbase + (size_t)mi * 16 * S_ + ks * 32 + lg * 8);
#pragma unroll
            for (int ni = 0; ni < 4; ++ni) {
                int dd = ni * 16 + lr;
                bf16x8 kf = *(const bf16x8*)(lds + head * 32768 + dd * 512 +
                                             ((ks * 64 + lg * 16) ^ ((dd & 7) << 4)));
                akv[0][ni] = __builtin_amdgcn_mfma_f32_16x16x32_bf16(vf[0], kf, akv[0][ni], 0, 0, 0);
                akv[1][ni] = __builtin_amdgcn_mfma_f32_16x16x32_bf16(vf[1], kf, akv[1][ni], 0, 0, 0);
            }
        }
        float* kvp = KVP + ((size_t)(tm & 15) * 64 + bh) * 4096;
#pragma unroll
        for (int mi = 0; mi < 2; ++mi)
#pragma unroll
            for (int ni = 0; ni < 4; ++ni)
#pragma unroll
                for (int j = 0; j < 4; ++j)
                    kvp[(mh * 32 + mi * 16 + lg * 4 + j) * 64 + ni * 16 + lr] = akv[mi][ni][j];
        int hd = t >> 7, dd2 = (t >> 1) & 63, hf = t & 1;
        float ksm = 0.f;
#pragma unroll
        for (int i = 0; i < 16; ++i) {
            bf16x8 kk8 = *(const bf16x8*)(lds + hd * 32768 + dd2 * 512 +
                                          ((hf * 256 + i * 16) ^ ((dd2 & 7) << 4)));
#pragma unroll
            for (int e = 0; e < 8; ++e) ksm += b2f((u16)kk8[e]);
        }
        ksm += __shfl_xor(ksm, 1);
        if (!hf) KSP[(tm & 15) * 4096 + (b * 16 + g * 4 + hd) * 64 + dd2] = ksm;
    }
    __syncthreads();

    // ===== tile Q -> KQ (row-major bf16) =====
    {
        int n0 = g * 256;
        const u16* gB = Wbf + (size_t)(n0 + srow) * K_ + scolE;
        f32x4 acc[8][4] = {};
        run_tile(gA, gB, lds, t16, aB, bB, pc0, pc1, acc);
        float bv[4];
#pragma unroll
        for (int ni = 0; ni < 4; ++ni) bv[ni] = bias[n0 + wc * 64 + ni * 16 + lr];
#pragma unroll
        for (int mi = 0; mi < 8; ++mi)
#pragma unroll
            for (int j = 0; j < 4; ++j) {
                int row = m0 + wr * 128 + mi * 16 + lg * 4 + j;
#pragma unroll
                for (int ni = 0; ni < 4; ++ni) {
                    int col = n0 + wc * 64 + ni * 16 + lr;
                    KQ[(size_t)row * E_ + col] = f2b(phi_f(acc[mi][ni][j] + bv[ni]));
                }
            }
    }
}

// ---------------- kernel 3: deterministic partial reduce ----------------
__global__ void reduce_kv(const float* __restrict__ KVP, const float* __restrict__ KSP,
                          float* __restrict__ KV, float* __restrict__ KSUM)
{
    int g = blockIdx.x * 256 + threadIdx.x;   // 65536 threads
#pragma unroll 1
    for (int i = g * 4; i < g * 4 + 4; ++i) {
        float s = 0.f;
#pragma unroll
        for (int c = 0; c < 16; ++c) s += KVP[(size_t)c * (64 * 4096) + i];
        KV[i] = s;
    }
    if (g < 4096) {
        float s = 0.f;
#pragma unroll
        for (int c = 0; c < 16; ++c) s += KSP[c * 4096 + g];
        KSUM[g] = s;
    }
}

// ---------------- kernel 4: attn = kq·[kv;ksum] , divide by den ----------------
__global__ __launch_bounds__(256) void attn_out(
    const u16* __restrict__ KQ, const float* __restrict__ KV,
    const float* __restrict__ KSUM, float* __restrict__ Out)
{
    __shared__ __align__(16) u16 kqs[16384];   // 256 x 64 bf16 (32 KB)
    __shared__ __align__(16) u16 bsm[5120];    // 80 x 64 bf16
    __shared__ float den[256];
    int bh = blockIdx.x, ch = blockIdx.y;
    int b = bh >> 4, h = bh & 15;
    int t = threadIdx.x;
    int l = t & 63, w = t >> 6;
    int lg = l >> 4, lr = l & 15;
    size_t row0 = (size_t)b * S_ + ch * 256;
    int srow = t >> 3, scol = (t & 7) << 3;
#pragma unroll
    for (int i = 0; i < 8; ++i)
        gload16(KQ + (row0 + srow + i * 32) * E_ + h * 64 + scol, kqs + i * 2048 + t * 8);

    const float* kvg = KV + bh * 4096;
#pragma unroll
    for (int ii = 0; ii < 16; ii += 4) {
        float4 v = *(const float4*)(kvg + t * 16 + ii);
        u16x4 o; o[0] = f2b(v.x); o[1] = f2b(v.y); o[2] = f2b(v.z); o[3] = f2b(v.w);
        *(u16x4*)&bsm[t * 16 + ii] = o;
    }
    if (t < 64) bsm[4096 + t] = f2b(KSUM[bh * 64 + t]);
    for (int i = t; i < 960; i += 256) bsm[4160 + i] = 0;
    __syncthreads();

    f32x4 acc[4][5] = {};
#pragma unroll
    for (int kh = 0; kh < 2; ++kh) {
        int ko = kh * 32 + lg * 8;
        bf16x8 af[4];
#pragma unroll
        for (int mi = 0; mi < 4; ++mi)
            af[mi] = *(const bf16x8*)&kqs[(w * 64 + mi * 16 + lr) * 64 + ko];
#pragma unroll
        for (int ni = 0; ni < 5; ++ni) {
            bf16x8 bb = *(const bf16x8*)&bsm[(ni * 16 + lr) * 64 + ko];
#pragma unroll
            for (int mi = 0; mi < 4; ++mi)
                acc[mi][ni] = __builtin_amdgcn_mfma_f32_16x16x32_bf16(af[mi], bb, acc[mi][ni], 0, 0, 0);
        }
    }
    if (lr == 0) {
#pragma unroll
        for (int mi = 0; mi < 4; ++mi)
#pragma unroll
            for (int j = 0; j < 4; ++j)
                den[w * 64 + mi * 16 + lg * 4 + j] = acc[mi][4][j];
    }
    __syncthreads();
#pragma unroll
    for (int mi = 0; mi < 4; ++mi)
#pragma unroll
        for (int j = 0; j < 4; ++j) {
            int sl = w * 64 + mi * 16 + lg * 4 + j;
            float z = 1.f / (den[sl] + 1e-6f);
            float* op = Out + (row0 + sl) * E_ + h * 64;
#pragma unroll
            for (int ni = 0; ni < 4; ++ni)
                op[ni * 16 + lr] = acc[mi][ni][j] * z;
        }
}

extern "C" void kernel_launch(void* const* d_in, const int* in_sizes, int n_in,
                              void* d_out, int out_size, void* d_ws, size_t ws_size,
                              hipStream_t stream)
{
    const float* inputs = (const float*)d_in[0];
    const float* mask   = (const float*)d_in[1];
    const float* w_qkv  = (const float*)d_in[2];
    const float* b_qkv  = (const float*)d_in[3];

    u16* Abf = (u16*)d_ws;                          // 16777216 bf16 (32 MB)
    u16* Wbf = Abf + (size_t)M_ * K_;               // 3145728 bf16 (6 MB)
    u16* KQ  = Wbf + (size_t)N_ * K_;               // 16777216 bf16 (32 MB)
    float* KVP  = (float*)(KQ + (size_t)M_ * E_);   // 16*262144 f32 (16 MB)
    float* KSP  = KVP + 16 * 64 * 4096;             // 16*4096 f32
    float* KV   = KSP + 16 * 4096;                  // 262144 f32
    float* KSUM = KV + 64 * 4096;                   // 4096 f32

    // V^T lives in d_out (bf16), consumed inside gemm_fused only;
    // attn_out overwrites d_out with the final fp32 output.
    u16* VT = (u16*)d_out;

    cvt_bf16<<<2048, 256, 0, stream>>>(inputs, Abf, M_ * K_ / 8);
    cvt_bf16<<<768, 256, 0, stream>>>(w_qkv, Wbf, N_ * K_ / 8);
    gemm_fused<<<256, 512, 0, stream>>>(Abf, Wbf, b_qkv, mask, KQ, VT, KVP, KSP);
    reduce_kv<<<256, 256, 0, stream>>>(KVP, KSP, KV, KSUM);
    attn_out<<<dim3(64, 16), 256, 0, stream>>>(KQ, KV, KSUM, (float*)d_out);
}